// Round 1
// baseline (180.335 us; speedup 1.0000x reference)
//
#include <hip/hip_runtime.h>
#include <hip/hip_fp16.h>

// CochainMessagePassing: out[b,n,i,h,j] = softmax_j( sum_k a2[b,n,h,i,k] * x[b,n,j,h*64+k] )
// (e_self adds a per-row constant before softmax over j -> cancels exactly; a1 is unused.)
//
// B*N_NB = 16, H = 8 -> 128 "bnh" matrices of 1024x1024, K = 64.

typedef _Float16 half8 __attribute__((ext_vector_type(8)));
typedef float floatx4 __attribute__((ext_vector_type(4)));

#define N_C   1024
#define D_H   64

// ---------------------------------------------------------------------------
// prep: gather heads, fp32 -> fp16.
//   xh16[bnh][j][k]  (k pre-swizzled: octet ^= j&7, so main kernel's linear
//                     global_load_lds + swizzled ds_read_b128 is conflict-free)
//   a216[bnh][i][k]  (linear; read direct global->reg as A-fragments)
// 2^21 tasks, 8 halves each.
__global__ __launch_bounds__(256) void prep_kernel(
    const float* __restrict__ x, const float* __restrict__ aw,
    _Float16* __restrict__ xh16, _Float16* __restrict__ a216)
{
  int t = blockIdx.x * 256 + threadIdx.x;
  int which = t >> 20;           // 0: xh, 1: a2
  int r   = t & 0xFFFFF;
  int kk  = r & 7;               // k-octet
  int row = (r >> 3) & 1023;
  int bnh = r >> 13;             // 0..127
  const float* src;
  _Float16* dst;
  if (which == 0) {
    int bn = bnh >> 3, h = bnh & 7;
    src = x + ((size_t)(bn * N_C + row) * 512) + h * 64 + kk * 8;
    dst = xh16 + ((size_t)(bnh * N_C + row) * 64) + ((kk ^ (row & 7)) * 8);
  } else {
    src = aw + ((size_t)(bnh * N_C + row) * 128) + 64 + kk * 8;
    dst = a216 + ((size_t)(bnh * N_C + row) * 64) + kk * 8;
  }
  const float4* s4 = (const float4*)src;
  float4 u = s4[0], v = s4[1];
  half8 hv;
  hv[0] = (_Float16)u.x; hv[1] = (_Float16)u.y;
  hv[2] = (_Float16)u.z; hv[3] = (_Float16)u.w;
  hv[4] = (_Float16)v.x; hv[5] = (_Float16)v.y;
  hv[6] = (_Float16)v.z; hv[7] = (_Float16)v.w;
  *(half8*)dst = hv;
}

// ---------------------------------------------------------------------------
// main: one block per (bnh, 16-row i-tile). 4 waves; wave w owns cols
// j = c*256 + w*64 + f*16 + (lane&15), c=0..3 chunks, f=0..3 col-frags.
// Full 1024-col rows live in registers -> fused softmax, zero score re-read.
__global__ __launch_bounds__(256) void attn_kernel(
    const _Float16* __restrict__ xh16, const _Float16* __restrict__ a216,
    float* __restrict__ out)
{
  __shared__ __align__(16) _Float16 lds[256 * 64];   // 32 KiB chunk buffer
  __shared__ float redmax[4][16];
  __shared__ float redsum[4][16];

  const int bx  = blockIdx.x;
  const int bnh = bx >> 6;
  const int it  = bx & 63;
  const int bn  = bnh >> 3, h = bnh & 7;
  const int tid = threadIdx.x;
  const int w    = tid >> 6;
  const int lane = tid & 63;
  const int l16  = lane & 15;
  const int lq   = lane >> 4;

  // A fragments: a2 rows of this i-tile. mfma_f32_16x16x32_f16 A layout:
  // lane holds A[row = lane&15][k = 8*(lane>>4) + e], second k-step +32.
  const _Float16* a2p = a216 + (size_t)bnh * (N_C * 64) + (size_t)(it * 16 + l16) * 64;
  half8 afrag0 = *(const half8*)(a2p + lq * 8);
  half8 afrag1 = *(const half8*)(a2p + 32 + lq * 8);

  floatx4 acc[16];
  #pragma unroll
  for (int i = 0; i < 16; ++i) acc[i] = floatx4{0.f, 0.f, 0.f, 0.f};

  const char* xbase = (const char*)(xh16 + (size_t)bnh * (N_C * 64));
  char* ldsb = (char*)lds;

  for (int c = 0; c < 4; ++c) {
    // stage chunk c: 256 rows x 128 B = 32 KiB, linear (ws is pre-swizzled)
    #pragma unroll
    for (int q = 0; q < 8; ++q) {
      int seg = (w * 8 + q) * 1024;   // wave-uniform LDS dest; +lane*16 by HW
      __builtin_amdgcn_global_load_lds(
          (const __attribute__((address_space(1))) unsigned int*)
              (xbase + (size_t)c * 32768 + seg + lane * 16),
          (__attribute__((address_space(3))) unsigned int*)(ldsb + seg),
          16, 0, 0);
    }
    __syncthreads();   // drains vmcnt before barrier (compiler-enforced)

    #pragma unroll
    for (int f = 0; f < 4; ++f) {
      int row = w * 64 + f * 16 + l16;          // B lane holds col(=xh row) lane&15
      const half8 b0 = *(const half8*)(ldsb + row * 128 + (((lq    ) ^ (row & 7)) << 4));
      const half8 b1 = *(const half8*)(ldsb + row * 128 + (((lq + 4) ^ (row & 7)) << 4));
      acc[c*4+f] = __builtin_amdgcn_mfma_f32_16x16x32_f16(afrag0, b0, acc[c*4+f], 0, 0, 0);
      acc[c*4+f] = __builtin_amdgcn_mfma_f32_16x16x32_f16(afrag1, b1, acc[c*4+f], 0, 0, 0);
    }
    __syncthreads();   // all reads done before next chunk overwrites
  }

  // ---- fused softmax over j. C/D layout: col = lane&15, row = lq*4 + reg.
  // Lane holds 4 rows x 16 cols. Reduce: in-register (16) -> shfl_xor over the
  // 16-lane col group -> tiny LDS across the 4 waves.
  float rmax[4], rsum[4];
  #pragma unroll
  for (int ri = 0; ri < 4; ++ri) {
    float m = acc[0][ri];
    #pragma unroll
    for (int cf = 1; cf < 16; ++cf) m = fmaxf(m, acc[cf][ri]);
    #pragma unroll
    for (int off = 1; off < 16; off <<= 1) m = fmaxf(m, __shfl_xor(m, off));
    rmax[ri] = m;
  }
  if (l16 == 0) {
    #pragma unroll
    for (int ri = 0; ri < 4; ++ri) redmax[w][lq * 4 + ri] = rmax[ri];
  }
  __syncthreads();
  #pragma unroll
  for (int ri = 0; ri < 4; ++ri) {
    int lr = lq * 4 + ri;
    rmax[ri] = fmaxf(fmaxf(redmax[0][lr], redmax[1][lr]),
                     fmaxf(redmax[2][lr], redmax[3][lr]));
  }
  #pragma unroll
  for (int ri = 0; ri < 4; ++ri) {
    float s = 0.f;
    #pragma unroll
    for (int cf = 0; cf < 16; ++cf) {
      float e = __expf(acc[cf][ri] - rmax[ri]);
      acc[cf][ri] = e;
      s += e;
    }
    #pragma unroll
    for (int off = 1; off < 16; off <<= 1) s += __shfl_xor(s, off);
    rsum[ri] = s;
  }
  if (l16 == 0) {
    #pragma unroll
    for (int ri = 0; ri < 4; ++ri) redsum[w][lq * 4 + ri] = rsum[ri];
  }
  __syncthreads();
  #pragma unroll
  for (int ri = 0; ri < 4; ++ri) {
    int lr = lq * 4 + ri;
    rsum[ri] = 1.0f / (redsum[0][lr] + redsum[1][lr] + redsum[2][lr] + redsum[3][lr]);
  }

  // ---- store out[b][n][i][h][j], fp32
  #pragma unroll
  for (int ri = 0; ri < 4; ++ri) {
    int ig = it * 16 + lq * 4 + ri;
    size_t base = (((size_t)(bn * N_C + ig) * 8 + h) * N_C) + w * 64 + l16;
    float inv = rsum[ri];
    #pragma unroll
    for (int c = 0; c < 4; ++c) {
      #pragma unroll
      for (int f = 0; f < 4; ++f)
        out[base + c * 256 + f * 16] = acc[c * 4 + f][ri] * inv;
    }
  }
}

// ---------------------------------------------------------------------------
extern "C" void kernel_launch(void* const* d_in, const int* in_sizes, int n_in,
                              void* d_out, int out_size, void* d_ws, size_t ws_size,
                              hipStream_t stream) {
  const float* x  = (const float*)d_in[0];   // (4,4,1024,512)
  const float* aw = (const float*)d_in[1];   // (4,4,8,1024,128)
  float* out = (float*)d_out;                // (4,4,1024,8,1024)

  _Float16* xh16 = (_Float16*)d_ws;                           // 16 MiB
  _Float16* a216 = (_Float16*)d_ws + (size_t)128 * N_C * 64;  // 16 MiB

  prep_kernel<<<8192, 256, 0, stream>>>(x, aw, xh16, a216);   // 2^21 tasks
  attn_kernel<<<8192, 256, 0, stream>>>(xh16, a216, out);     // 128 bnh x 64 i-tiles
}